// Round 9
// baseline (184.040 us; speedup 1.0000x reference)
//
#include <hip/hip_runtime.h>
#include <stdint.h>

// CSSA: B=32, H=W=64, C=64, heads=4, hd=16, strip windows 64x8 -> 256 windows.
// Round 14: r13 structure (74us, best: block=(window,head,q-half), 2048x512,
// 4 blocks/CU) + r6's LDS layouts back. r13's frag-blocked tiles were
// mod-32-WRONG: quad*64 shorts = 32 dw == 0 mod 32 banks (quad never
// separates banks -> 4-way on frag reads) and the epilogue's 72 taps/thread
// hit 16-tokens-per-2-banks = 8-way each -> 7.2M conflict-cycles ~= 12us.
// r6 strides serve BOTH patterns: KSTR2=20 (dw stride 10: 5*l15+quad mod 16
// spreads all bank-pairs, ~min 4/bank on b64 reads); VSTR=520 (dw stride 260
// == 4 mod 32: frag reads ~4/bank; epilogue taps: 16 consecutive tokens span
// 8 banks x 2 lanes = FREE). V staged channel-major (r13 trick, retargeted):
// lane=(d,tokgroup) reads 4 coalesced 64B lines -> one us4 write (~min banks).
// QK^T transposed (A=K,B=Q) so P's C-layout == K=16 B-frag layout: PV MFMA
// consumes P straight from registers. Epilogue r6-lean, no index arrays.
#define KSTR2 20    // K row: 16 ch + 4 pad (40 B)
#define VSTR  520   // Vt row: 512 tok + 8 pad

typedef __attribute__((ext_vector_type(4))) short          short4v;
typedef __attribute__((ext_vector_type(4))) float          f32x4;
typedef __attribute__((ext_vector_type(4))) unsigned short us4;
typedef __bf16 bf2_t __attribute__((ext_vector_type(2)));

__device__ __forceinline__ float bf2f(unsigned short u) {
    union { unsigned int i; float f; } x; x.i = ((unsigned int)u) << 16; return x.f;
}
__device__ __forceinline__ unsigned int pk2bf(float lo, float hi) {
#if __has_builtin(__builtin_amdgcn_cvt_pk_bf16_f32)
    union { bf2_t v; unsigned int u; } c;
    c.v = __builtin_amdgcn_cvt_pk_bf16_f32(lo, hi);     // 1 VALU op
    return c.u;
#else
    union { float f; unsigned int u; } a, b; a.f = lo; b.f = hi;
    return __builtin_amdgcn_perm(b.u + 0x8000u, a.u + 0x8000u, 0x07060302u);
#endif
}
__device__ __forceinline__ short4v pk4bf(float a, float b, float c, float d) {
    union { short4v s; unsigned int u[2]; } p;
    p.u[0] = pk2bf(a, b);
    p.u[1] = pk2bf(c, d);
    return p.s;
}

__global__ __launch_bounds__(512, 6)
void CSSA_69355131896243_kernel(const float* __restrict__ qkv,
                                const float* __restrict__ wconv,
                                const float* __restrict__ bconv,
                                float* __restrict__ out)
{
    __shared__ unsigned short Kl[512 * KSTR2];   // 20480 B  K[token][d] bf16
    __shared__ unsigned short Vt[16 * VSTR];     // 16640 B  V^T[d][token] bf16
    __shared__ float Wl[144];                    // head's 16x9 conv weights
    __shared__ float Bl[16];

    const int tid  = threadIdx.x;
    const int wave = tid >> 6, lane = tid & 63, quad = lane >> 4, l15 = lane & 15;

    // bid = x + 8*s + 64*y: x=0..7, s=(head,qh) 0..7, y=0..31. The 8 s-siblings
    // of a window are adjacent in dispatch -> same XCD -> shared K/V reads and
    // head-sibling output sectors merge in L2 (r13: WRITE_SIZE == ideal).
    const int bid  = blockIdx.x;
    const int x    = bid & 7, s = (bid >> 3) & 7, y = bid >> 6;
    const int head = s & 3, qh = s >> 2;
    const int win  = x * 32 + y;
    const int b    = win >> 3, wx = win & 7;
    const int hc   = head * 16;

    const size_t ONE  = (size_t)32 * 4096 * 64;
    const size_t base = ((size_t)b * 4096 + (size_t)wx * 8) * 64;
    const float* gQ = qkv + base;
    const float* gK = qkv + ONE + base;
    const float* gV = qkv + 2 * ONE + base;

    // ---- stage K rows: thread=(t0=tid>>2, c4=tid&3), 128 tokens/round ----
    {
        const int c4 = tid & 3;
        const int t0 = tid >> 2;
        #pragma unroll
        for (int r = 0; r < 4; ++r) {
            const int t = r * 128 + t0;
            const size_t goff = (size_t)(t >> 3) * 4096 + (size_t)(t & 7) * 64 + hc + c4 * 4;
            f32x4 kd = *(const f32x4*)(gK + goff);
            union { us4 v; unsigned int u[2]; } kb;
            kb.u[0] = pk2bf(kd[0], kd[1]);
            kb.u[1] = pk2bf(kd[2], kd[3]);
            *(us4*)(&Kl[t * KSTR2 + c4 * 4]) = kb.v;
        }
        // ---- stage V^T channel-major: lane=(d=tid&15, g=tid>>4 + 32r) ----
        const int d = tid & 15;
        #pragma unroll
        for (int r = 0; r < 4; ++r) {
            const int g = (tid >> 4) + r * 32;          // token group: t=g*4+i
            const float* src = gV + (size_t)(g >> 1) * 4096 + (size_t)((g & 1) * 4) * 64 + hc + d;
            const float v0 = src[0], v1 = src[64], v2 = src[128], v3 = src[192];
            union { us4 v; unsigned int u[2]; } vb;
            vb.u[0] = pk2bf(v0, v1);
            vb.u[1] = pk2bf(v2, v3);
            *(us4*)(&Vt[d * VSTR + g * 4]) = vb.v;      // 4 consecutive tokens
        }
    }
    if (tid < 144) Wl[tid] = wconv[head * 144 + tid];
    if (tid < 16)  Bl[tid] = bconv[hc + tid];

    // ---- Q prefetch + pack (independent of LDS -> overlaps barrier wait) ----
    const float SCL = 0.25f * 1.44269504088896341f;   // scale*log2(e) folded in
    const int q0 = qh * 256 + wave * 32;
    short4v qf[2];   // B[k=d=quad*4+i][n=q=l15]
    #pragma unroll
    for (int t = 0; t < 2; ++t) {
        const int q = q0 + t * 16 + l15;
        f32x4 qv = *(const f32x4*)(gQ + (size_t)(q >> 3) * 4096 + (size_t)(q & 7) * 64 + hc + quad * 4);
        qf[t] = pk4bf(qv[0] * SCL, qv[1] * SCL, qv[2] * SCL, qv[3] * SCL);
    }
    __syncthreads();

    f32x4 acc[2];
    float lp[2];
    #pragma unroll
    for (int t = 0; t < 2; ++t) { acc[t] = (f32x4)0.0f; lp[t] = 0.0f; }

    // ---- main loop: 32 chunks x 16 keys, frags from LDS (imm offsets) ----
    #pragma unroll 4
    for (int c = 0; c < 32; ++c) {
        // K A-frag: A[m=key=l15][k=d=quad*4+i]
        const short4v kf = *(const short4v*)(&Kl[(c * 16 + l15) * KSTR2 + quad * 4]);
        // V A-frag: A[m=d=l15][k=key=quad*4+i]
        const short4v vf = *(const short4v*)(&Vt[l15 * VSTR + c * 16 + quad * 4]);
        #pragma unroll
        for (int t = 0; t < 2; ++t) {
            // s^T[key][q]: C row=quad*4+j -> key, col=l15 -> q
            f32x4 sc = __builtin_amdgcn_mfma_f32_16x16x16bf16_1k(kf, qf[t], (f32x4)0.0f, 0, 0, 0);
            const float p0 = __builtin_amdgcn_exp2f(sc[0]);
            const float p1 = __builtin_amdgcn_exp2f(sc[1]);
            const float p2 = __builtin_amdgcn_exp2f(sc[2]);
            const float p3 = __builtin_amdgcn_exp2f(sc[3]);
            lp[t] += (p0 + p1) + (p2 + p3);
            // P C-layout == K=16 B-frag layout -> PV straight from registers
            acc[t] = __builtin_amdgcn_mfma_f32_16x16x16bf16_1k(vf, pk4bf(p0, p1, p2, p3), acc[t], 0, 0, 0);
        }
    }

    // ---- denominators: cross-quad reduce ----
    float linv[2];
    #pragma unroll
    for (int t = 0; t < 2; ++t) {
        float v = lp[t];
        v += __shfl_xor(v, 16, 64);
        v += __shfl_xor(v, 32, 64);
        linv[t] = __builtin_amdgcn_rcpf(v);
    }

    // ---- epilogue: LePE from resident V^T rows (taps bank-free), store ----
    #pragma unroll
    for (int j = 0; j < 4; ++j) {
        const int d = quad * 4 + j;
        float w9[9];
        #pragma unroll
        for (int o = 0; o < 9; ++o) w9[o] = Wl[d * 9 + o];
        const float bs = Bl[d];
        const unsigned short* vrow = &Vt[d * VSTR];
        #pragma unroll
        for (int t = 0; t < 2; ++t) {
            const int q = q0 + t * 16 + l15;
            const int yy0 = q >> 3, xx0 = l15 & 7;
            float lep = bs;
            #pragma unroll
            for (int dy = 0; dy < 3; ++dy) {
                #pragma unroll
                for (int dx = 0; dx < 3; ++dx) {
                    const int yy = yy0 + dy - 1, xx = xx0 + dx - 1;
                    const bool ok = ((unsigned)yy < 64u) && ((unsigned)xx < 8u);
                    const int tt = (q + (dy - 1) * 8 + (dx - 1)) & 511;   // masked if OOB
                    lep += (ok ? w9[dy * 3 + dx] : 0.0f) * bf2f(vrow[tt]);
                }
            }
            acc[t][j] = acc[t][j] * linv[t] + lep;
        }
    }
    float* gO = out + base;
    #pragma unroll
    for (int t = 0; t < 2; ++t) {
        const int q = q0 + t * 16 + l15;
        *(f32x4*)(gO + (size_t)(q >> 3) * 4096 + (size_t)(q & 7) * 64 + hc + quad * 4) = acc[t];
    }
}

extern "C" void kernel_launch(void* const* d_in, const int* in_sizes, int n_in,
                              void* d_out, int out_size, void* d_ws, size_t ws_size,
                              hipStream_t stream) {
    const float* qkv   = (const float*)d_in[0];
    const float* wconv = (const float*)d_in[1];
    const float* bconv = (const float*)d_in[2];
    float* outp = (float*)d_out;
    hipLaunchKernelGGL(CSSA_69355131896243_kernel, dim3(2048), dim3(512), 0, stream,
                       qkv, wconv, bconv, outp);
}